// Round 3
// baseline (192.320 us; speedup 1.0000x reference)
//
#include <hip/hip_runtime.h>
#include <hip/hip_bf16.h>
#include <stdint.h>

typedef short  short8  __attribute__((ext_vector_type(8)));
typedef float  floatx4 __attribute__((ext_vector_type(4)));

// d_ws byte layout (all bf16 except bias fp32 at end)
#define WS_W0_ROT   0        // [128][32]  natural k-order
#define WS_W0_TRZ   8192
#define WS_W1_ROT   16384    // [128][128] sigma k-order
#define WS_W1_TRZ   49152
#define WS_W2_ROT   81920    // [16][128]  sigma k-order, rows 9..15 zero
#define WS_W2_TRZ   86016    // rows 3..15 zero
#define WS_BIAS     90112    // fp32: [ob0(128) ob1(128) ob2p(16) tb0 tb1 tb2p] = 544

__device__ __forceinline__ unsigned short f2bf_rne(float f) {
    union { float f; unsigned u; } v; v.f = f;
    unsigned r = v.u + 0x7fffu + ((v.u >> 16) & 1u);
    return (unsigned short)(r >> 16);
}

// ---------------- prep: fp32 weights -> bf16 swizzled in ws ----------------
__global__ void prep_kernel(const float* __restrict__ ow0, const float* __restrict__ ow1,
                            const float* __restrict__ ow2, const float* __restrict__ tw0,
                            const float* __restrict__ tw1, const float* __restrict__ tw2,
                            const float* __restrict__ ob0, const float* __restrict__ ob1,
                            const float* __restrict__ ob2, const float* __restrict__ tb0,
                            const float* __restrict__ tb1, const float* __restrict__ tb2,
                            unsigned char* __restrict__ ws)
{
    int t = blockIdx.x * 256 + threadIdx.x;
    unsigned short* w16 = (unsigned short*)ws;
    if (t < 4096) {                      // ow0 natural [n][k]
        w16[t] = f2bf_rne(ow0[t]);
    } else if (t < 8192) {               // tw0
        w16[t] = f2bf_rne(tw0[t - 4096]);
    } else if (t < 24576) {              // ow1 sigma: ws[n][p] = W[n][(p&7)*16 + (p>>3)]
        int i = t - 8192; int n = i >> 7, p = i & 127;
        w16[t] = f2bf_rne(ow1[n * 128 + ((p & 7) << 4) + (p >> 3)]);
    } else if (t < 40960) {              // tw1 sigma
        int i = t - 24576; int n = i >> 7, p = i & 127;
        w16[t] = f2bf_rne(tw1[n * 128 + ((p & 7) << 4) + (p >> 3)]);
    } else if (t < 43008) {              // ow2 sigma, pad n>=9 with 0
        int i = t - 40960; int n = i >> 7, p = i & 127;
        w16[t] = (n < 9) ? f2bf_rne(ow2[n * 128 + ((p & 7) << 4) + (p >> 3)]) : (unsigned short)0;
    } else if (t < 45056) {              // tw2 sigma, pad n>=3 with 0
        int i = t - 43008; int n = i >> 7, p = i & 127;
        w16[t] = (n < 3) ? f2bf_rne(tw2[n * 128 + ((p & 7) << 4) + (p >> 3)]) : (unsigned short)0;
    } else if (t < 45600) {              // biases fp32, padded
        int i = t - 45056;
        float v;
        if      (i < 128) v = ob0[i];
        else if (i < 256) v = ob1[i - 128];
        else if (i < 272) v = (i - 256 < 9) ? ob2[i - 256] : 0.0f;
        else if (i < 400) v = tb0[i - 272];
        else if (i < 528) v = tb1[i - 400];
        else              v = (i - 528 < 3) ? tb2[i - 528] : 0.0f;
        ((float*)(ws + WS_BIAS))[i] = v;
    }
}

// ---------------- main fused kernel ----------------
__device__ __forceinline__ floatx4 mfma16(short8 a, short8 b, floatx4 c) {
    return __builtin_amdgcn_mfma_f32_16x16x32_bf16(a, b, c, 0, 0, 0);
}

__device__ __forceinline__ unsigned packbf2(float lo, float hi) {
    union { __hip_bfloat162 b2; unsigned u; } c;
    c.b2 = __float22bfloat162_rn(make_float2(lo, hi));
    return c.u;
}

__device__ __forceinline__ short8 pack8(floatx4 a, floatx4 b) {
    union { unsigned u[4]; short8 s; } r;
    r.u[0] = packbf2(a[0], a[1]);
    r.u[1] = packbf2(a[2], a[3]);
    r.u[2] = packbf2(b[0], b[1]);
    r.u[3] = packbf2(b[2], b[3]);
    return r.s;
}

// Write one layer's relu'd output (8 feature-tiles, full 16B chunks) for this
// lane's 4 rows. h layout: row m (16 rows) x 16 chunks of 16B; chunk c of row
// m stored at chunk' = c ^ (m&15).
__device__ __forceinline__ void write_h_b128(char* hb, int q, int ln,
                                             const floatx4* acc) {
    #pragma unroll
    for (int r = 0; r < 4; ++r) {
        const int m = q * 4 + r;
        union { unsigned u[4]; short8 s; } pk;
        #pragma unroll
        for (int j = 0; j < 4; ++j)
            pk.u[j] = packbf2(fmaxf(acc[2 * j][r], 0.0f), fmaxf(acc[2 * j + 1][r], 0.0f));
        const int cp = ln ^ (m & 15);
        *(short8*)(hb + m * 256 + cp * 16) = pk.s;
    }
}

// n-split variant: this wave owns features nt_glob = half*4 + (0..3), i.e. the
// bytes [half*8, half*8+8) of each swizzled 16B chunk (chunk packs feats
// {k*16+ln, k=0..7} as bf16 pairs). Writes 8B per row -> ds_write_b64.
__device__ __forceinline__ void write_h_b64_half(char* hb, int q, int ln, int half,
                                                 const floatx4* acc) {
    #pragma unroll
    for (int r = 0; r < 4; ++r) {
        const int m = q * 4 + r;
        uint2 pk;
        pk.x = packbf2(fmaxf(acc[0][r], 0.0f), fmaxf(acc[1][r], 0.0f));
        pk.y = packbf2(fmaxf(acc[2][r], 0.0f), fmaxf(acc[3][r], 0.0f));
        const int cp = ln ^ (m & 15);
        *(uint2*)(hb + m * 256 + cp * 16 + half * 8) = pk;
    }
}

__device__ __forceinline__ void read_a_b128(const char* hb, int q, int ln, short8* a) {
    #pragma unroll
    for (int s2 = 0; s2 < 4; ++s2) {
        const int cp = (s2 * 4 + q) ^ (ln & 15);
        a[s2] = *(const short8*)(hb + ln * 256 + cp * 16);
    }
}

__device__ __forceinline__ void mat3mul(float* C, const float* A, const float* B) {
    #pragma unroll
    for (int i = 0; i < 3; ++i)
        #pragma unroll
        for (int j = 0; j < 3; ++j)
            C[i*3+j] = A[i*3+0]*B[0+j] + A[i*3+1]*B[3+j] + A[i*3+2]*B[6+j];
}

// Wave layout: wv0,1 = rot pair, wv2,3 = trz pair. A pair processes all 128
// rows of the WG together, 32 rows per iteration (wave `half` does L0/L2 for
// its own 16-row group). L1 is feature-split: each wave holds only HALF of W1
// (16 short8 = 64 VGPRs) and computes its 64 output features for BOTH groups;
// halves merge through the swizzled lds_h chunks.
//
// 128 rows/WG (was 256): 1024 WGs -> 4096 waves over 1024 SIMDs = 4 waves/SIMD
// (was 2). The kernel is latency/barrier-bound (MfmaUtil ~7%, VALUBusy ~18%),
// so doubling co-resident waves is the lever. LDS 38.9 KB -> 4 blocks/CU fit;
// VGPR must stay <= 128 for 16 waves/CU (round-1 codegen was exactly 128).
__launch_bounds__(256, 3)
__global__ void fused_main(const float* __restrict__ y,
                           const unsigned char* __restrict__ ws,
                           float* __restrict__ out)
{
    // [mlp][phase(h1/h2)][group][16 rows x 256B]
    __shared__ __align__(16) unsigned char lds_h[2][2][2][4096];
    __shared__ __align__(16) float lds_stage[128 * 12];    // per-row [9 omega | 3 trz]

    const int tid  = threadIdx.x;
    const int wv   = tid >> 6;
    const int lane = tid & 63;
    const int ln   = lane & 15;
    const int q    = lane >> 4;
    const int mlp  = wv >> 1;   // 0 = rot, 1 = trz
    const int half = wv & 1;    // feature half for L1, row group for L0/L2
    const int wgbase = blockIdx.x * 128;

    const int W0_OFF = mlp ? WS_W0_TRZ : WS_W0_ROT;
    const int W1_OFF = mlp ? WS_W1_TRZ : WS_W1_ROT;
    const int W2_OFF = mlp ? WS_W2_TRZ : WS_W2_ROT;
    const float* bias = (const float*)(ws + WS_BIAS) + (mlp ? 272 : 0);

    // ---- persistent B-fragments: 8 + 16 + 4 = 28 short8 = 112 regs ----
    short8 bw0[8], bw1[16], bw2[4];
    #pragma unroll
    for (int nt = 0; nt < 8; ++nt)
        bw0[nt] = *(const short8*)(ws + W0_OFF + ((nt * 16 + ln) * 32 + q * 8) * 2);
    #pragma unroll
    for (int nt = 0; nt < 4; ++nt) {
        #pragma unroll
        for (int s2 = 0; s2 < 4; ++s2)
            bw1[nt * 4 + s2] = *(const short8*)(ws + W1_OFF +
                (((half * 4 + nt) * 16 + ln) * 128 + s2 * 32 + q * 8) * 2);
    }
    #pragma unroll
    for (int s2 = 0; s2 < 4; ++s2)
        bw2[s2] = *(const short8*)(ws + W2_OFF + (ln * 128 + s2 * 32 + q * 8) * 2);

    float b0v[8], b1v[4];
    #pragma unroll
    for (int nt = 0; nt < 8; ++nt) b0v[nt] = bias[nt * 16 + ln];
    #pragma unroll
    for (int nt = 0; nt < 4; ++nt) b1v[nt] = bias[128 + (half * 4 + nt) * 16 + ln];
    const float b2v = bias[256 + ln];

    char* const hbase   = (char*)&lds_h[mlp][0][0][0];
    char* const h0_mine = hbase + half * 4096;            // h1 buffer, my group
    char* const h1_mine = hbase + 8192 + half * 4096;     // h2 buffer, my group

    const int cb     = mlp ? 9 : 0;
    const int nvalid = mlp ? 3 : 9;

    // y addressing: row = wgbase + iter*32 + half*16 + ln, col = mlp*32 + q*8
    const float* ybase = y + (size_t)(wgbase + half * 16 + ln) * 64 + mlp * 32 + q * 8;

    auto body = [&](int iter, short8 a0) {
        // ---- layer 0 (row-split: my 16 rows, full 128 features) ----
        floatx4 acc0[8];
        #pragma unroll
        for (int nt = 0; nt < 8; ++nt) {
            const float b = b0v[nt];
            floatx4 c = {b, b, b, b};
            acc0[nt] = mfma16(a0, bw0[nt], c);
        }
        write_h_b128(h0_mine, q, ln, acc0);
        __syncthreads();   // h1 complete (both groups)

        // ---- layer 1 (feature-split: my 64 features, both 16-row groups) ----
        floatx4 acc1[2][4];
        #pragma unroll
        for (int g2 = 0; g2 < 2; ++g2) {
            #pragma unroll
            for (int nt = 0; nt < 4; ++nt) {
                const float b = b1v[nt];
                floatx4 c = {b, b, b, b};
                acc1[g2][nt] = c;
            }
        }
        #pragma unroll
        for (int g2 = 0; g2 < 2; ++g2) {
            const char* src = hbase + g2 * 4096;
            #pragma unroll
            for (int s2 = 0; s2 < 4; ++s2) {
                const int cp = (s2 * 4 + q) ^ ln;
                short8 a1 = *(const short8*)(src + ln * 256 + cp * 16);
                #pragma unroll
                for (int nt = 0; nt < 4; ++nt)
                    acc1[g2][nt] = mfma16(a1, bw1[nt * 4 + s2], acc1[g2][nt]);
            }
        }
        #pragma unroll
        for (int g2 = 0; g2 < 2; ++g2)
            write_h_b64_half(hbase + 8192 + g2 * 4096, q, ln, half, acc1[g2]);
        __syncthreads();   // h2 complete (both halves merged)

        // ---- layer 2 (row-split: my 16 rows, 16 outputs) ----
        short8 a2[4];
        read_a_b128(h1_mine, q, ln, a2);
        floatx4 acc2 = {b2v, b2v, b2v, b2v};
        #pragma unroll
        for (int s2 = 0; s2 < 4; ++s2)
            acc2 = mfma16(a2[s2], bw2[s2], acc2);

        if (ln < nvalid) {
            const int rl = iter * 32 + half * 16 + q * 4;
            #pragma unroll
            for (int r = 0; r < 4; ++r)
                lds_stage[(rl + r) * 12 + cb + ln] = acc2[r];
        }
    };

    // depth-2 y prefetch: one 32-row iteration = 2048 floats stride
    floatx4 c00 = *(const floatx4*)(ybase);
    floatx4 c01 = *(const floatx4*)(ybase + 4);
    floatx4 c10 = *(const floatx4*)(ybase + 2048);
    floatx4 c11 = *(const floatx4*)(ybase + 2052);

    #pragma unroll 1
    for (int it2 = 0; it2 < 2; ++it2) {
        {
            short8 a0 = pack8(c00, c01);
            if (it2 < 1) {
                const float* p = ybase + (size_t)(it2 * 2 + 2) * 2048;
                c00 = *(const floatx4*)(p);
                c01 = *(const floatx4*)(p + 4);
            }
            body(it2 * 2, a0);
        }
        {
            short8 a0 = pack8(c10, c11);
            if (it2 < 1) {
                const float* p = ybase + (size_t)(it2 * 2 + 3) * 2048;
                c10 = *(const floatx4*)(p);
                c11 = *(const floatx4*)(p + 4);
            }
            body(it2 * 2 + 1, a0);
        }
    }

    __syncthreads();

    // ---- expm: one row per thread (128 rows/WG, threads 0..127) ----
    if (tid < 128) {
        float* st = &lds_stage[tid * 12];
        floatx4 m0 = *(floatx4*)(st);
        floatx4 m1 = *(floatx4*)(st + 4);
        floatx4 m2 = *(floatx4*)(st + 8);
        float M[9] = {m0[0], m0[1], m0[2], m0[3], m1[0], m1[1], m1[2], m1[3], m2[0]};
        const float tz0 = m2[1], tz1 = m2[2], tz2 = m2[3];

        float r0 = fabsf(M[0]) + fabsf(M[1]) + fabsf(M[2]);
        float r1 = fabsf(M[3]) + fabsf(M[4]) + fabsf(M[5]);
        float r2 = fabsf(M[6]) + fabsf(M[7]) + fabsf(M[8]);
        float nrm = fmaxf(r0, fmaxf(r1, r2));
        int e; (void)frexpf(nrm, &e);
        int s = e + 1;
        if (s < 0) s = 0;
        if (s > 24) s = 24;
        float sc;
        { union { unsigned u; float f; } cv; cv.u = (unsigned)(127 - s) << 23; sc = cv.f; }
        #pragma unroll
        for (int i = 0; i < 9; ++i) M[i] *= sc;

        float Rm[9];
        #pragma unroll
        for (int i = 0; i < 9; ++i) Rm[i] = 0.0f;
        Rm[0] = Rm[4] = Rm[8] = 1.0f;
        #pragma unroll
        for (int j = 12; j >= 1; --j) {
            float T[9]; mat3mul(T, M, Rm);
            const float inv = 1.0f / (float)j;
            #pragma unroll
            for (int i = 0; i < 9; ++i) Rm[i] = T[i] * inv;
            Rm[0] += 1.0f; Rm[4] += 1.0f; Rm[8] += 1.0f;
        }
        for (int it = 0; it < s; ++it) {
            float T[9]; mat3mul(T, Rm, Rm);
            #pragma unroll
            for (int i = 0; i < 9; ++i) Rm[i] = T[i];
        }

        floatx4 o0 = {Rm[0], Rm[1], Rm[2], Rm[3]};
        floatx4 o1 = {Rm[4], Rm[5], Rm[6], Rm[7]};
        floatx4 o2 = {Rm[8], tz0, tz1, tz2};
        *(floatx4*)(st)     = o0;
        *(floatx4*)(st + 4) = o1;
        *(floatx4*)(st + 8) = o2;
    }

    __syncthreads();

    // ---- fully-coalesced output: 384 contiguous 16B chunks per WG ----
    {
        float* ob = out + (size_t)wgbase * 12;
        #pragma unroll
        for (int k = 0; k < 2; ++k) {
            const int j = k * 256 + tid;
            if (j < 384) {
                floatx4 v = *(floatx4*)&lds_stage[j * 4];
                *(floatx4*)(ob + j * 4) = v;
            }
        }
    }
}

extern "C" void kernel_launch(void* const* d_in, const int* in_sizes, int n_in,
                              void* d_out, int out_size, void* d_ws, size_t ws_size,
                              hipStream_t stream)
{
    const float* y = (const float*)d_in[0];
    prep_kernel<<<179, 256, 0, stream>>>(
        (const float*)d_in[1], (const float*)d_in[3], (const float*)d_in[5],
        (const float*)d_in[7], (const float*)d_in[9], (const float*)d_in[11],
        (const float*)d_in[2], (const float*)d_in[4], (const float*)d_in[6],
        (const float*)d_in[8], (const float*)d_in[10], (const float*)d_in[12],
        (unsigned char*)d_ws);
    fused_main<<<1024, 256, 0, stream>>>(y, (const unsigned char*)d_ws, (float*)d_out);
}

// Round 4
// 119.943 us; speedup vs baseline: 1.6034x; 1.6034x over previous
//
#include <hip/hip_runtime.h>
#include <hip/hip_bf16.h>
#include <stdint.h>

typedef short  short8  __attribute__((ext_vector_type(8)));
typedef float  floatx4 __attribute__((ext_vector_type(4)));

// d_ws byte layout (all bf16 except bias fp32 at end)
#define WS_W0_ROT   0        // [128][32]  natural k-order
#define WS_W0_TRZ   8192
#define WS_W1_ROT   16384    // [128][128] sigma k-order
#define WS_W1_TRZ   49152
#define WS_W2_ROT   81920    // [16][128]  sigma k-order, rows 9..15 zero
#define WS_W2_TRZ   86016    // rows 3..15 zero
#define WS_BIAS     90112    // fp32: [ob0(128) ob1(128) ob2p(16) tb0 tb1 tb2p] = 544

__device__ __forceinline__ unsigned short f2bf_rne(float f) {
    union { float f; unsigned u; } v; v.f = f;
    unsigned r = v.u + 0x7fffu + ((v.u >> 16) & 1u);
    return (unsigned short)(r >> 16);
}

// ---------------- prep: fp32 weights -> bf16 swizzled in ws ----------------
__global__ void prep_kernel(const float* __restrict__ ow0, const float* __restrict__ ow1,
                            const float* __restrict__ ow2, const float* __restrict__ tw0,
                            const float* __restrict__ tw1, const float* __restrict__ tw2,
                            const float* __restrict__ ob0, const float* __restrict__ ob1,
                            const float* __restrict__ ob2, const float* __restrict__ tb0,
                            const float* __restrict__ tb1, const float* __restrict__ tb2,
                            unsigned char* __restrict__ ws)
{
    int t = blockIdx.x * 256 + threadIdx.x;
    unsigned short* w16 = (unsigned short*)ws;
    if (t < 4096) {                      // ow0 natural [n][k]
        w16[t] = f2bf_rne(ow0[t]);
    } else if (t < 8192) {               // tw0
        w16[t] = f2bf_rne(tw0[t - 4096]);
    } else if (t < 24576) {              // ow1 sigma: ws[n][p] = W[n][(p&7)*16 + (p>>3)]
        int i = t - 8192; int n = i >> 7, p = i & 127;
        w16[t] = f2bf_rne(ow1[n * 128 + ((p & 7) << 4) + (p >> 3)]);
    } else if (t < 40960) {              // tw1 sigma
        int i = t - 24576; int n = i >> 7, p = i & 127;
        w16[t] = f2bf_rne(tw1[n * 128 + ((p & 7) << 4) + (p >> 3)]);
    } else if (t < 43008) {              // ow2 sigma, pad n>=9 with 0
        int i = t - 40960; int n = i >> 7, p = i & 127;
        w16[t] = (n < 9) ? f2bf_rne(ow2[n * 128 + ((p & 7) << 4) + (p >> 3)]) : (unsigned short)0;
    } else if (t < 45056) {              // tw2 sigma, pad n>=3 with 0
        int i = t - 43008; int n = i >> 7, p = i & 127;
        w16[t] = (n < 3) ? f2bf_rne(tw2[n * 128 + ((p & 7) << 4) + (p >> 3)]) : (unsigned short)0;
    } else if (t < 45600) {              // biases fp32, padded
        int i = t - 45056;
        float v;
        if      (i < 128) v = ob0[i];
        else if (i < 256) v = ob1[i - 128];
        else if (i < 272) v = (i - 256 < 9) ? ob2[i - 256] : 0.0f;
        else if (i < 400) v = tb0[i - 272];
        else if (i < 528) v = tb1[i - 400];
        else              v = (i - 528 < 3) ? tb2[i - 528] : 0.0f;
        ((float*)(ws + WS_BIAS))[i] = v;
    }
}

// ---------------- main fused kernel ----------------
__device__ __forceinline__ floatx4 mfma16(short8 a, short8 b, floatx4 c) {
    return __builtin_amdgcn_mfma_f32_16x16x32_bf16(a, b, c, 0, 0, 0);
}

__device__ __forceinline__ unsigned packbf2(float lo, float hi) {
    union { __hip_bfloat162 b2; unsigned u; } c;
    c.b2 = __float22bfloat162_rn(make_float2(lo, hi));
    return c.u;
}

__device__ __forceinline__ short8 pack8(floatx4 a, floatx4 b) {
    union { unsigned u[4]; short8 s; } r;
    r.u[0] = packbf2(a[0], a[1]);
    r.u[1] = packbf2(a[2], a[3]);
    r.u[2] = packbf2(b[0], b[1]);
    r.u[3] = packbf2(b[2], b[3]);
    return r.s;
}

// Write one layer's relu'd output (8 feature-tiles, full 16B chunks) for this
// lane's 4 rows. h layout: row m (16 rows) x 16 chunks of 16B; chunk c of row
// m stored at chunk' = c ^ (m&15).
__device__ __forceinline__ void write_h_b128(char* hb, int q, int ln,
                                             const floatx4* acc) {
    #pragma unroll
    for (int r = 0; r < 4; ++r) {
        const int m = q * 4 + r;
        union { unsigned u[4]; short8 s; } pk;
        #pragma unroll
        for (int j = 0; j < 4; ++j)
            pk.u[j] = packbf2(fmaxf(acc[2 * j][r], 0.0f), fmaxf(acc[2 * j + 1][r], 0.0f));
        const int cp = ln ^ (m & 15);
        *(short8*)(hb + m * 256 + cp * 16) = pk.s;
    }
}

// n-split variant: this wave owns features nt_glob = half*4 + (0..3), i.e. the
// bytes [half*8, half*8+8) of each swizzled 16B chunk (chunk packs feats
// {k*16+ln, k=0..7} as bf16 pairs). Writes 8B per row -> ds_write_b64.
__device__ __forceinline__ void write_h_b64_half(char* hb, int q, int ln, int half,
                                                 const floatx4* acc) {
    #pragma unroll
    for (int r = 0; r < 4; ++r) {
        const int m = q * 4 + r;
        uint2 pk;
        pk.x = packbf2(fmaxf(acc[0][r], 0.0f), fmaxf(acc[1][r], 0.0f));
        pk.y = packbf2(fmaxf(acc[2][r], 0.0f), fmaxf(acc[3][r], 0.0f));
        const int cp = ln ^ (m & 15);
        *(uint2*)(hb + m * 256 + cp * 16 + half * 8) = pk;
    }
}

__device__ __forceinline__ void read_a_b128(const char* hb, int q, int ln, short8* a) {
    #pragma unroll
    for (int s2 = 0; s2 < 4; ++s2) {
        const int cp = (s2 * 4 + q) ^ (ln & 15);
        a[s2] = *(const short8*)(hb + ln * 256 + cp * 16);
    }
}

__device__ __forceinline__ void mat3mul(float* C, const float* A, const float* B) {
    #pragma unroll
    for (int i = 0; i < 3; ++i)
        #pragma unroll
        for (int j = 0; j < 3; ++j)
            C[i*3+j] = A[i*3+0]*B[0+j] + A[i*3+1]*B[3+j] + A[i*3+2]*B[6+j];
}

// Wave layout: wv0,1 = rot pair, wv2,3 = trz pair. A pair processes all 128
// rows of the WG together, 32 rows per iteration (wave `half` does L0/L2 for
// its own 16-row group). L1 is feature-split: each wave holds only HALF of W1
// (16 short8 = 64 VGPRs) and computes its 64 output features for BOTH groups;
// halves merge through the swizzled lds_h chunks.
//
// 128 rows/WG, 1024 WGs: up to 4 blocks/CU capacity (LDS 38.9KB x 4 = 156KB).
// CRITICAL: launch bound stays (256,2). Round 3's (256,3) capped the unified
// VGPR+AGPR file below the ~230-reg live set and spilled the persistent
// weights to scratch (FETCH 139MB, WRITE 95MB, 106us). The natural allocation
// for this body is 128 VGPR (round 1), which the HW can run at 4 waves/SIMD
// without any forced cap.
__launch_bounds__(256, 2)
__global__ void fused_main(const float* __restrict__ y,
                           const unsigned char* __restrict__ ws,
                           float* __restrict__ out)
{
    // [mlp][phase(h1/h2)][group][16 rows x 256B]
    __shared__ __align__(16) unsigned char lds_h[2][2][2][4096];
    __shared__ __align__(16) float lds_stage[128 * 12];    // per-row [9 omega | 3 trz]

    const int tid  = threadIdx.x;
    const int wv   = tid >> 6;
    const int lane = tid & 63;
    const int ln   = lane & 15;
    const int q    = lane >> 4;
    const int mlp  = wv >> 1;   // 0 = rot, 1 = trz
    const int half = wv & 1;    // feature half for L1, row group for L0/L2
    const int wgbase = blockIdx.x * 128;

    const int W0_OFF = mlp ? WS_W0_TRZ : WS_W0_ROT;
    const int W1_OFF = mlp ? WS_W1_TRZ : WS_W1_ROT;
    const int W2_OFF = mlp ? WS_W2_TRZ : WS_W2_ROT;
    const float* bias = (const float*)(ws + WS_BIAS) + (mlp ? 272 : 0);

    // ---- persistent B-fragments: 8 + 16 + 4 = 28 short8 = 112 regs ----
    short8 bw0[8], bw1[16], bw2[4];
    #pragma unroll
    for (int nt = 0; nt < 8; ++nt)
        bw0[nt] = *(const short8*)(ws + W0_OFF + ((nt * 16 + ln) * 32 + q * 8) * 2);
    #pragma unroll
    for (int nt = 0; nt < 4; ++nt) {
        #pragma unroll
        for (int s2 = 0; s2 < 4; ++s2)
            bw1[nt * 4 + s2] = *(const short8*)(ws + W1_OFF +
                (((half * 4 + nt) * 16 + ln) * 128 + s2 * 32 + q * 8) * 2);
    }
    #pragma unroll
    for (int s2 = 0; s2 < 4; ++s2)
        bw2[s2] = *(const short8*)(ws + W2_OFF + (ln * 128 + s2 * 32 + q * 8) * 2);

    float b0v[8], b1v[4];
    #pragma unroll
    for (int nt = 0; nt < 8; ++nt) b0v[nt] = bias[nt * 16 + ln];
    #pragma unroll
    for (int nt = 0; nt < 4; ++nt) b1v[nt] = bias[128 + (half * 4 + nt) * 16 + ln];
    const float b2v = bias[256 + ln];

    char* const hbase   = (char*)&lds_h[mlp][0][0][0];
    char* const h0_mine = hbase + half * 4096;            // h1 buffer, my group
    char* const h1_mine = hbase + 8192 + half * 4096;     // h2 buffer, my group

    const int cb     = mlp ? 9 : 0;
    const int nvalid = mlp ? 3 : 9;

    // y addressing: row = wgbase + iter*32 + half*16 + ln, col = mlp*32 + q*8
    const float* ybase = y + (size_t)(wgbase + half * 16 + ln) * 64 + mlp * 32 + q * 8;

    auto body = [&](int iter, short8 a0) {
        // ---- layer 0 (row-split: my 16 rows, full 128 features) ----
        floatx4 acc0[8];
        #pragma unroll
        for (int nt = 0; nt < 8; ++nt) {
            const float b = b0v[nt];
            floatx4 c = {b, b, b, b};
            acc0[nt] = mfma16(a0, bw0[nt], c);
        }
        write_h_b128(h0_mine, q, ln, acc0);
        __syncthreads();   // h1 complete (both groups)

        // ---- layer 1 (feature-split: my 64 features, both 16-row groups) ----
        floatx4 acc1[2][4];
        #pragma unroll
        for (int g2 = 0; g2 < 2; ++g2) {
            #pragma unroll
            for (int nt = 0; nt < 4; ++nt) {
                const float b = b1v[nt];
                floatx4 c = {b, b, b, b};
                acc1[g2][nt] = c;
            }
        }
        #pragma unroll
        for (int g2 = 0; g2 < 2; ++g2) {
            const char* src = hbase + g2 * 4096;
            #pragma unroll
            for (int s2 = 0; s2 < 4; ++s2) {
                const int cp = (s2 * 4 + q) ^ ln;
                short8 a1 = *(const short8*)(src + ln * 256 + cp * 16);
                #pragma unroll
                for (int nt = 0; nt < 4; ++nt)
                    acc1[g2][nt] = mfma16(a1, bw1[nt * 4 + s2], acc1[g2][nt]);
            }
        }
        #pragma unroll
        for (int g2 = 0; g2 < 2; ++g2)
            write_h_b64_half(hbase + 8192 + g2 * 4096, q, ln, half, acc1[g2]);
        __syncthreads();   // h2 complete (both halves merged)

        // ---- layer 2 (row-split: my 16 rows, 16 outputs) ----
        short8 a2[4];
        read_a_b128(h1_mine, q, ln, a2);
        floatx4 acc2 = {b2v, b2v, b2v, b2v};
        #pragma unroll
        for (int s2 = 0; s2 < 4; ++s2)
            acc2 = mfma16(a2[s2], bw2[s2], acc2);

        if (ln < nvalid) {
            const int rl = iter * 32 + half * 16 + q * 4;
            #pragma unroll
            for (int r = 0; r < 4; ++r)
                lds_stage[(rl + r) * 12 + cb + ln] = acc2[r];
        }
    };

    // depth-2 y prefetch: one 32-row iteration = 2048 floats stride
    floatx4 c00 = *(const floatx4*)(ybase);
    floatx4 c01 = *(const floatx4*)(ybase + 4);
    floatx4 c10 = *(const floatx4*)(ybase + 2048);
    floatx4 c11 = *(const floatx4*)(ybase + 2052);

    #pragma unroll 1
    for (int it2 = 0; it2 < 2; ++it2) {
        {
            short8 a0 = pack8(c00, c01);
            if (it2 < 1) {
                const float* p = ybase + (size_t)(it2 * 2 + 2) * 2048;
                c00 = *(const floatx4*)(p);
                c01 = *(const floatx4*)(p + 4);
            }
            body(it2 * 2, a0);
        }
        {
            short8 a0 = pack8(c10, c11);
            if (it2 < 1) {
                const float* p = ybase + (size_t)(it2 * 2 + 3) * 2048;
                c10 = *(const floatx4*)(p);
                c11 = *(const floatx4*)(p + 4);
            }
            body(it2 * 2 + 1, a0);
        }
    }

    __syncthreads();

    // ---- expm: one row per thread (128 rows/WG, threads 0..127) ----
    if (tid < 128) {
        float* st = &lds_stage[tid * 12];
        floatx4 m0 = *(floatx4*)(st);
        floatx4 m1 = *(floatx4*)(st + 4);
        floatx4 m2 = *(floatx4*)(st + 8);
        float M[9] = {m0[0], m0[1], m0[2], m0[3], m1[0], m1[1], m1[2], m1[3], m2[0]};
        const float tz0 = m2[1], tz1 = m2[2], tz2 = m2[3];

        float r0 = fabsf(M[0]) + fabsf(M[1]) + fabsf(M[2]);
        float r1 = fabsf(M[3]) + fabsf(M[4]) + fabsf(M[5]);
        float r2 = fabsf(M[6]) + fabsf(M[7]) + fabsf(M[8]);
        float nrm = fmaxf(r0, fmaxf(r1, r2));
        int e; (void)frexpf(nrm, &e);
        int s = e + 1;
        if (s < 0) s = 0;
        if (s > 24) s = 24;
        float sc;
        { union { unsigned u; float f; } cv; cv.u = (unsigned)(127 - s) << 23; sc = cv.f; }
        #pragma unroll
        for (int i = 0; i < 9; ++i) M[i] *= sc;

        float Rm[9];
        #pragma unroll
        for (int i = 0; i < 9; ++i) Rm[i] = 0.0f;
        Rm[0] = Rm[4] = Rm[8] = 1.0f;
        #pragma unroll
        for (int j = 12; j >= 1; --j) {
            float T[9]; mat3mul(T, M, Rm);
            const float inv = 1.0f / (float)j;
            #pragma unroll
            for (int i = 0; i < 9; ++i) Rm[i] = T[i] * inv;
            Rm[0] += 1.0f; Rm[4] += 1.0f; Rm[8] += 1.0f;
        }
        for (int it = 0; it < s; ++it) {
            float T[9]; mat3mul(T, Rm, Rm);
            #pragma unroll
            for (int i = 0; i < 9; ++i) Rm[i] = T[i];
        }

        floatx4 o0 = {Rm[0], Rm[1], Rm[2], Rm[3]};
        floatx4 o1 = {Rm[4], Rm[5], Rm[6], Rm[7]};
        floatx4 o2 = {Rm[8], tz0, tz1, tz2};
        *(floatx4*)(st)     = o0;
        *(floatx4*)(st + 4) = o1;
        *(floatx4*)(st + 8) = o2;
    }

    __syncthreads();

    // ---- fully-coalesced output: 384 contiguous 16B chunks per WG ----
    {
        float* ob = out + (size_t)wgbase * 12;
        #pragma unroll
        for (int k = 0; k < 2; ++k) {
            const int j = k * 256 + tid;
            if (j < 384) {
                floatx4 v = *(floatx4*)&lds_stage[j * 4];
                *(floatx4*)(ob + j * 4) = v;
            }
        }
    }
}

extern "C" void kernel_launch(void* const* d_in, const int* in_sizes, int n_in,
                              void* d_out, int out_size, void* d_ws, size_t ws_size,
                              hipStream_t stream)
{
    const float* y = (const float*)d_in[0];
    prep_kernel<<<179, 256, 0, stream>>>(
        (const float*)d_in[1], (const float*)d_in[3], (const float*)d_in[5],
        (const float*)d_in[7], (const float*)d_in[9], (const float*)d_in[11],
        (const float*)d_in[2], (const float*)d_in[4], (const float*)d_in[6],
        (const float*)d_in[8], (const float*)d_in[10], (const float*)d_in[12],
        (unsigned char*)d_ws);
    fused_main<<<1024, 256, 0, stream>>>(y, (const unsigned char*)d_ws, (float*)d_out);
}

// Round 5
// 114.412 us; speedup vs baseline: 1.6809x; 1.0483x over previous
//
#include <hip/hip_runtime.h>
#include <hip/hip_bf16.h>
#include <stdint.h>

typedef short  short8  __attribute__((ext_vector_type(8)));
typedef float  floatx4 __attribute__((ext_vector_type(4)));

// d_ws byte layout (all bf16 except bias fp32 at end)
#define WS_W0_ROT   0        // [128][32]  natural k-order
#define WS_W0_TRZ   8192
#define WS_W1_ROT   16384    // [128][128] sigma k-order
#define WS_W1_TRZ   49152
#define WS_W2_ROT   81920    // [16][128]  sigma k-order, rows 9..15 zero
#define WS_W2_TRZ   86016    // rows 3..15 zero
#define WS_BIAS     90112    // fp32: [ob0(128) ob1(128) ob2p(16) tb0 tb1 tb2p] = 544

__device__ __forceinline__ unsigned short f2bf_rne(float f) {
    union { float f; unsigned u; } v; v.f = f;
    unsigned r = v.u + 0x7fffu + ((v.u >> 16) & 1u);
    return (unsigned short)(r >> 16);
}

// ---------------- prep: fp32 weights -> bf16 swizzled in ws ----------------
__global__ void prep_kernel(const float* __restrict__ ow0, const float* __restrict__ ow1,
                            const float* __restrict__ ow2, const float* __restrict__ tw0,
                            const float* __restrict__ tw1, const float* __restrict__ tw2,
                            const float* __restrict__ ob0, const float* __restrict__ ob1,
                            const float* __restrict__ ob2, const float* __restrict__ tb0,
                            const float* __restrict__ tb1, const float* __restrict__ tb2,
                            unsigned char* __restrict__ ws)
{
    int t = blockIdx.x * 256 + threadIdx.x;
    unsigned short* w16 = (unsigned short*)ws;
    if (t < 4096) {                      // ow0 natural [n][k]
        w16[t] = f2bf_rne(ow0[t]);
    } else if (t < 8192) {               // tw0
        w16[t] = f2bf_rne(tw0[t - 4096]);
    } else if (t < 24576) {              // ow1 sigma: ws[n][p] = W[n][(p&7)*16 + (p>>3)]
        int i = t - 8192; int n = i >> 7, p = i & 127;
        w16[t] = f2bf_rne(ow1[n * 128 + ((p & 7) << 4) + (p >> 3)]);
    } else if (t < 40960) {              // tw1 sigma
        int i = t - 24576; int n = i >> 7, p = i & 127;
        w16[t] = f2bf_rne(tw1[n * 128 + ((p & 7) << 4) + (p >> 3)]);
    } else if (t < 43008) {              // ow2 sigma, pad n>=9 with 0
        int i = t - 40960; int n = i >> 7, p = i & 127;
        w16[t] = (n < 9) ? f2bf_rne(ow2[n * 128 + ((p & 7) << 4) + (p >> 3)]) : (unsigned short)0;
    } else if (t < 45056) {              // tw2 sigma, pad n>=3 with 0
        int i = t - 43008; int n = i >> 7, p = i & 127;
        w16[t] = (n < 3) ? f2bf_rne(tw2[n * 128 + ((p & 7) << 4) + (p >> 3)]) : (unsigned short)0;
    } else if (t < 45600) {              // biases fp32, padded
        int i = t - 45056;
        float v;
        if      (i < 128) v = ob0[i];
        else if (i < 256) v = ob1[i - 128];
        else if (i < 272) v = (i - 256 < 9) ? ob2[i - 256] : 0.0f;
        else if (i < 400) v = tb0[i - 272];
        else if (i < 528) v = tb1[i - 400];
        else              v = (i - 528 < 3) ? tb2[i - 528] : 0.0f;
        ((float*)(ws + WS_BIAS))[i] = v;
    }
}

// ---------------- main fused kernel ----------------
__device__ __forceinline__ floatx4 mfma16(short8 a, short8 b, floatx4 c) {
    return __builtin_amdgcn_mfma_f32_16x16x32_bf16(a, b, c, 0, 0, 0);
}

__device__ __forceinline__ unsigned packbf2(float lo, float hi) {
    union { __hip_bfloat162 b2; unsigned u; } c;
    c.b2 = __float22bfloat162_rn(make_float2(lo, hi));
    return c.u;
}

__device__ __forceinline__ short8 pack8(floatx4 a, floatx4 b) {
    union { unsigned u[4]; short8 s; } r;
    r.u[0] = packbf2(a[0], a[1]);
    r.u[1] = packbf2(a[2], a[3]);
    r.u[2] = packbf2(b[0], b[1]);
    r.u[3] = packbf2(b[2], b[3]);
    return r.s;
}

// Write one layer's relu'd output (8 feature-tiles, full 16B chunks) for this
// lane's 4 rows. h layout: row m (16 rows) x 16 chunks of 16B; chunk c of row
// m stored at chunk' = c ^ (m&15).
__device__ __forceinline__ void write_h_b128(char* hb, int q, int ln,
                                             const floatx4* acc) {
    #pragma unroll
    for (int r = 0; r < 4; ++r) {
        const int m = q * 4 + r;
        union { unsigned u[4]; short8 s; } pk;
        #pragma unroll
        for (int j = 0; j < 4; ++j)
            pk.u[j] = packbf2(fmaxf(acc[2 * j][r], 0.0f), fmaxf(acc[2 * j + 1][r], 0.0f));
        const int cp = ln ^ (m & 15);
        *(short8*)(hb + m * 256 + cp * 16) = pk.s;
    }
}

// n-split variant: this wave owns features nt_glob = half*4 + (0..3), i.e. the
// bytes [half*8, half*8+8) of each swizzled 16B chunk. ds_write_b64 per row.
__device__ __forceinline__ void write_h_b64_half(char* hb, int q, int ln, int half,
                                                 const floatx4* acc) {
    #pragma unroll
    for (int r = 0; r < 4; ++r) {
        const int m = q * 4 + r;
        uint2 pk;
        pk.x = packbf2(fmaxf(acc[0][r], 0.0f), fmaxf(acc[1][r], 0.0f));
        pk.y = packbf2(fmaxf(acc[2][r], 0.0f), fmaxf(acc[3][r], 0.0f));
        const int cp = ln ^ (m & 15);
        *(uint2*)(hb + m * 256 + cp * 16 + half * 8) = pk;
    }
}

__device__ __forceinline__ void read_a_b128(const char* hb, int q, int ln, short8* a) {
    #pragma unroll
    for (int s2 = 0; s2 < 4; ++s2) {
        const int cp = (s2 * 4 + q) ^ (ln & 15);
        a[s2] = *(const short8*)(hb + ln * 256 + cp * 16);
    }
}

__device__ __forceinline__ void mat3mul(float* C, const float* A, const float* B) {
    #pragma unroll
    for (int i = 0; i < 3; ++i)
        #pragma unroll
        for (int j = 0; j < 3; ++j)
            C[i*3+j] = A[i*3+0]*B[0+j] + A[i*3+1]*B[3+j] + A[i*3+2]*B[6+j];
}

// Wave layout: wv0,1 = rot pair, wv2,3 = trz pair; 256 rows/WG, 512 WGs.
// L1 feature-split as before (each wave holds half of W1 = 64 regs).
//
// SOFTWARE-PIPELINED SCHEDULE (1 barrier/iteration, was 2):
// Between consecutive barriers, three independent streams execute:
//   L2(g-1): read h2[(g-1)&1] -> 4 mfma -> stage
//   L1(g):   read h1[g&1]     -> 32 mfma -> write h2[g&1]
//   L0(g+1): pack y(g+1)      -> 8 mfma  -> write h1[(g+1)&1]
// h1 and h2 are both double-buffered, so every cross-iteration hazard is a
// WAR separated by exactly one barrier. Rationale: at ~192 total V+A regs the
// HW runs only 2 waves/SIMD no matter the grid (rounds 1/4), so occupancy
// can't hide the barrier chain -- instead we halve the barriers and give each
// region ~44 MFMA + all packing as schedulable ILP.
// LDS: 2 mlp * 4 slots (h1x2,h2x2) * 2 groups * 4KB = 64KB + 12KB stage
// = 77.8KB; 2 blocks/CU * 77.8 = 155.6 <= 160KB.
__launch_bounds__(256, 2)
__global__ void fused_main(const float* __restrict__ y,
                           const unsigned char* __restrict__ ws,
                           float* __restrict__ out)
{
    // [mlp][slot: h1b0,h1b1,h2b0,h2b1][group][16 rows x 256B]
    __shared__ __align__(16) unsigned char lds_h[2][4][2][4096];
    __shared__ __align__(16) float lds_stage[256 * 12];    // per-row [9 omega | 3 trz]

    const int tid  = threadIdx.x;
    const int wv   = tid >> 6;
    const int lane = tid & 63;
    const int ln   = lane & 15;
    const int q    = lane >> 4;
    const int mlp  = wv >> 1;   // 0 = rot, 1 = trz
    const int half = wv & 1;    // feature half for L1, row group for L0/L2
    const int wgbase = blockIdx.x * 256;

    const int W0_OFF = mlp ? WS_W0_TRZ : WS_W0_ROT;
    const int W1_OFF = mlp ? WS_W1_TRZ : WS_W1_ROT;
    const int W2_OFF = mlp ? WS_W2_TRZ : WS_W2_ROT;
    const float* bias = (const float*)(ws + WS_BIAS) + (mlp ? 272 : 0);

    // ---- persistent B-fragments: 8 + 16 + 4 = 28 short8 = 112 regs ----
    short8 bw0[8], bw1[16], bw2[4];
    #pragma unroll
    for (int nt = 0; nt < 8; ++nt)
        bw0[nt] = *(const short8*)(ws + W0_OFF + ((nt * 16 + ln) * 32 + q * 8) * 2);
    #pragma unroll
    for (int nt = 0; nt < 4; ++nt) {
        #pragma unroll
        for (int s2 = 0; s2 < 4; ++s2)
            bw1[nt * 4 + s2] = *(const short8*)(ws + W1_OFF +
                (((half * 4 + nt) * 16 + ln) * 128 + s2 * 32 + q * 8) * 2);
    }
    #pragma unroll
    for (int s2 = 0; s2 < 4; ++s2)
        bw2[s2] = *(const short8*)(ws + W2_OFF + (ln * 128 + s2 * 32 + q * 8) * 2);

    float b0v[8], b1v[4];
    #pragma unroll
    for (int nt = 0; nt < 8; ++nt) b0v[nt] = bias[nt * 16 + ln];
    #pragma unroll
    for (int nt = 0; nt < 4; ++nt) b1v[nt] = bias[128 + (half * 4 + nt) * 16 + ln];
    const float b2v = bias[256 + ln];

    char* const hbase = (char*)&lds_h[mlp][0][0][0];
    // slot s (0..3), group grp (0..1)
    auto H = [&](int s, int grp) -> char* { return hbase + (s * 2 + grp) * 4096; };

    const int cb     = mlp ? 9 : 0;
    const int nvalid = mlp ? 3 : 9;

    // y addressing: row = wgbase + g*32 + half*16 + ln, col = mlp*32 + q*8
    const float* ybase = y + (size_t)(wgbase + half * 16 + ln) * 64 + mlp * 32 + q * 8;

    // ---- pipeline stage lambdas ----
    auto do_l0 = [&](int gn, short8 a0) {          // L0 of iteration gn
        floatx4 acc0[8];
        #pragma unroll
        for (int nt = 0; nt < 8; ++nt) {
            const float b = b0v[nt];
            floatx4 c = {b, b, b, b};
            acc0[nt] = mfma16(a0, bw0[nt], c);
        }
        write_h_b128(H(gn & 1, half), q, ln, acc0);
    };
    auto do_l1 = [&](int g) {                      // L1 of iteration g
        floatx4 acc1[2][4];
        #pragma unroll
        for (int g2 = 0; g2 < 2; ++g2) {
            #pragma unroll
            for (int nt = 0; nt < 4; ++nt) {
                const float b = b1v[nt];
                floatx4 c = {b, b, b, b};
                acc1[g2][nt] = c;
            }
        }
        #pragma unroll
        for (int g2 = 0; g2 < 2; ++g2) {
            const char* src = H(g & 1, g2);
            #pragma unroll
            for (int s2 = 0; s2 < 4; ++s2) {
                const int cp = (s2 * 4 + q) ^ ln;
                short8 a1 = *(const short8*)(src + ln * 256 + cp * 16);
                #pragma unroll
                for (int nt = 0; nt < 4; ++nt)
                    acc1[g2][nt] = mfma16(a1, bw1[nt * 4 + s2], acc1[g2][nt]);
            }
        }
        #pragma unroll
        for (int g2 = 0; g2 < 2; ++g2)
            write_h_b64_half(H(2 + (g & 1), g2), q, ln, half, acc1[g2]);
    };
    auto do_l2 = [&](int gg) {                     // L2 of iteration gg
        short8 a2[4];
        read_a_b128(H(2 + (gg & 1), half), q, ln, a2);
        floatx4 acc2 = {b2v, b2v, b2v, b2v};
        #pragma unroll
        for (int s2 = 0; s2 < 4; ++s2)
            acc2 = mfma16(a2[s2], bw2[s2], acc2);
        if (ln < nvalid) {
            const int rl = gg * 32 + half * 16 + q * 4;
            #pragma unroll
            for (int r = 0; r < 4; ++r)
                lds_stage[(rl + r) * 12 + cb + ln] = acc2[r];
        }
    };

    // ---- y prefetch: cy holds even-consumed groups, dy odd (ping-pong) ----
    floatx4 cy0 = *(const floatx4*)(ybase);
    floatx4 cy1 = *(const floatx4*)(ybase + 4);
    floatx4 dy0 = *(const floatx4*)(ybase + 2048);
    floatx4 dy1 = *(const floatx4*)(ybase + 2052);

    // prologue: L0(0) from group 0; refill cy with group 2
    {
        short8 a0 = pack8(cy0, cy1);
        const float* p = ybase + (size_t)2 * 2048;
        cy0 = *(const floatx4*)(p);
        cy1 = *(const floatx4*)(p + 4);
        do_l0(0, a0);
    }
    __syncthreads();

    #pragma unroll 1
    for (int it2 = 0; it2 < 4; ++it2) {
        const int g = it2 * 2;
        {   // iteration g: L2(g-1) | L1(g) | L0(g+1) from dy (group g+1)
            short8 a0 = pack8(dy0, dy1);
            if (it2 < 3) {
                const float* p = ybase + (size_t)(g + 3) * 2048;
                dy0 = *(const floatx4*)(p);
                dy1 = *(const floatx4*)(p + 4);
            }
            if (it2 > 0) do_l2(g - 1);
            do_l1(g);
            do_l0(g + 1, a0);
            __syncthreads();
        }
        {   // iteration g+1: L2(g) | L1(g+1) | L0(g+2) from cy (group g+2)
            short8 a0 = {};
            if (it2 < 3) a0 = pack8(cy0, cy1);
            if (it2 < 2) {
                const float* p = ybase + (size_t)(g + 4) * 2048;
                cy0 = *(const floatx4*)(p);
                cy1 = *(const floatx4*)(p + 4);
            }
            do_l2(g);
            do_l1(g + 1);
            if (it2 < 3) do_l0(g + 2, a0);
            __syncthreads();
        }
    }
    // epilogue: L2(7)
    do_l2(7);
    __syncthreads();

    // ---- expm: one row per thread (256 rows/WG) ----
    {
        float* st = &lds_stage[tid * 12];
        floatx4 m0 = *(floatx4*)(st);
        floatx4 m1 = *(floatx4*)(st + 4);
        floatx4 m2 = *(floatx4*)(st + 8);
        float M[9] = {m0[0], m0[1], m0[2], m0[3], m1[0], m1[1], m1[2], m1[3], m2[0]};
        const float tz0 = m2[1], tz1 = m2[2], tz2 = m2[3];

        float r0 = fabsf(M[0]) + fabsf(M[1]) + fabsf(M[2]);
        float r1 = fabsf(M[3]) + fabsf(M[4]) + fabsf(M[5]);
        float r2 = fabsf(M[6]) + fabsf(M[7]) + fabsf(M[8]);
        float nrm = fmaxf(r0, fmaxf(r1, r2));
        int e; (void)frexpf(nrm, &e);
        int s = e + 1;
        if (s < 0) s = 0;
        if (s > 24) s = 24;
        float sc;
        { union { unsigned u; float f; } cv; cv.u = (unsigned)(127 - s) << 23; sc = cv.f; }
        #pragma unroll
        for (int i = 0; i < 9; ++i) M[i] *= sc;

        float Rm[9];
        #pragma unroll
        for (int i = 0; i < 9; ++i) Rm[i] = 0.0f;
        Rm[0] = Rm[4] = Rm[8] = 1.0f;
        #pragma unroll
        for (int j = 12; j >= 1; --j) {
            float T[9]; mat3mul(T, M, Rm);
            const float inv = 1.0f / (float)j;
            #pragma unroll
            for (int i = 0; i < 9; ++i) Rm[i] = T[i] * inv;
            Rm[0] += 1.0f; Rm[4] += 1.0f; Rm[8] += 1.0f;
        }
        for (int it = 0; it < s; ++it) {
            float T[9]; mat3mul(T, Rm, Rm);
            #pragma unroll
            for (int i = 0; i < 9; ++i) Rm[i] = T[i];
        }

        floatx4 o0 = {Rm[0], Rm[1], Rm[2], Rm[3]};
        floatx4 o1 = {Rm[4], Rm[5], Rm[6], Rm[7]};
        floatx4 o2 = {Rm[8], tz0, tz1, tz2};
        *(floatx4*)(st)     = o0;
        *(floatx4*)(st + 4) = o1;
        *(floatx4*)(st + 8) = o2;
    }

    __syncthreads();

    // ---- fully-coalesced output: 768 contiguous 16B chunks per WG ----
    {
        float* ob = out + (size_t)wgbase * 12;
        #pragma unroll
        for (int k = 0; k < 3; ++k) {
            const int j = k * 256 + tid;
            floatx4 v = *(floatx4*)&lds_stage[j * 4];
            *(floatx4*)(ob + j * 4) = v;
        }
    }
}

extern "C" void kernel_launch(void* const* d_in, const int* in_sizes, int n_in,
                              void* d_out, int out_size, void* d_ws, size_t ws_size,
                              hipStream_t stream)
{
    const float* y = (const float*)d_in[0];
    prep_kernel<<<179, 256, 0, stream>>>(
        (const float*)d_in[1], (const float*)d_in[3], (const float*)d_in[5],
        (const float*)d_in[7], (const float*)d_in[9], (const float*)d_in[11],
        (const float*)d_in[2], (const float*)d_in[4], (const float*)d_in[6],
        (const float*)d_in[8], (const float*)d_in[10], (const float*)d_in[12],
        (unsigned char*)d_ws);
    fused_main<<<512, 256, 0, stream>>>(y, (const unsigned char*)d_ws, (float*)d_out);
}